// Round 1
// baseline (892.529 us; speedup 1.0000x reference)
//
#include <hip/hip_runtime.h>
#include <math.h>

#define DFEAT 4096
#define BM 32
#define BK 32

// ---------------------------------------------------------------------------
// Kernel 1: per-row stats. One 256-thread block per row of 4096 floats.
// stats[r][0..9] = mean, std(ddof=1), min, max, lower-median, var, l2, l1, pos, neg
// ---------------------------------------------------------------------------
__global__ __launch_bounds__(256) void stats_kernel(const float* __restrict__ z,
                                                    float* __restrict__ stats)
{
    const int row = blockIdx.x;
    const int tid = threadIdx.x;

    __shared__ unsigned keys[4096];
    __shared__ unsigned hist[256];
    __shared__ unsigned scanbuf[256];
    __shared__ unsigned sh_bucket, sh_target;
    __shared__ float wred[4][7];

    const float* zr = z + (size_t)row * DFEAT;

    float sum = 0.f, sumsq = 0.f, l1 = 0.f;
    float mn = INFINITY, mx = -INFINITY;
    float pos = 0.f, neg = 0.f;

    #pragma unroll
    for (int j = 0; j < 4; ++j) {
        float4 v = reinterpret_cast<const float4*>(zr)[tid + j * 256];
        float vv[4] = {v.x, v.y, v.z, v.w};
        #pragma unroll
        for (int e = 0; e < 4; ++e) {
            float x = vv[e];
            sum += x;
            sumsq += x * x;
            l1 += fabsf(x);
            mn = fminf(mn, x);
            mx = fmaxf(mx, x);
            pos += (x > 0.f) ? 1.f : 0.f;
            neg += (x < 0.f) ? 1.f : 0.f;
            unsigned u = __float_as_uint(x);
            u = (u & 0x80000000u) ? ~u : (u | 0x80000000u);
            keys[(tid + j * 256) * 4 + e] = u;
        }
    }
    __syncthreads();

    // wave-level shuffle reduction (64 lanes)
    float tsum = sum, tss = sumsq, tl1 = l1, tmn = mn, tmx = mx, tpos = pos, tneg = neg;
    for (int off = 32; off > 0; off >>= 1) {
        tsum += __shfl_down(tsum, off);
        tss  += __shfl_down(tss,  off);
        tl1  += __shfl_down(tl1,  off);
        tmn = fminf(tmn, __shfl_down(tmn, off));
        tmx = fmaxf(tmx, __shfl_down(tmx, off));
        tpos += __shfl_down(tpos, off);
        tneg += __shfl_down(tneg, off);
    }
    const int wave = tid >> 6;
    if ((tid & 63) == 0) {
        wred[wave][0] = tsum; wred[wave][1] = tss; wred[wave][2] = tl1;
        wred[wave][3] = tmn;  wred[wave][4] = tmx; wred[wave][5] = tpos;
        wred[wave][6] = tneg;
    }
    __syncthreads();

    float fsum = 0.f, fss = 0.f, fl1 = 0.f, fpos = 0.f, fneg = 0.f;
    float fmn = INFINITY, fmx = -INFINITY;
    if (tid == 0) {
        #pragma unroll
        for (int w = 0; w < 4; ++w) {
            fsum += wred[w][0]; fss += wred[w][1]; fl1 += wred[w][2];
            fmn = fminf(fmn, wred[w][3]); fmx = fmaxf(fmx, wred[w][4]);
            fpos += wred[w][5]; fneg += wred[w][6];
        }
    }

    // ---- radix select: rank 2047 (lower median) over transformed keys ----
    unsigned prefix = 0;
    int target = (DFEAT - 1) / 2;   // 2047
    for (int shift = 24; shift >= 0; shift -= 8) {
        hist[tid] = 0;
        __syncthreads();
        const unsigned mask_hi = (shift == 24) ? 0u : (0xFFFFFFFFu << (shift + 8));
        #pragma unroll
        for (int j = 0; j < 16; ++j) {
            unsigned key = keys[tid + j * 256];
            if ((key & mask_hi) == prefix)
                atomicAdd(&hist[(key >> shift) & 255], 1u);
        }
        __syncthreads();
        unsigned v = hist[tid];
        scanbuf[tid] = v;
        __syncthreads();
        for (int off = 1; off < 256; off <<= 1) {
            unsigned t = (tid >= off) ? scanbuf[tid - off] : 0u;
            __syncthreads();
            scanbuf[tid] += t;
            __syncthreads();
        }
        const unsigned cum = scanbuf[tid];
        const unsigned prev = (tid == 0) ? 0u : scanbuf[tid - 1];
        if ((int)cum > target && (int)prev <= target) {
            sh_bucket = (unsigned)tid;
            sh_target = (unsigned)(target - (int)prev);
        }
        __syncthreads();
        prefix |= (sh_bucket << shift);
        target = (int)sh_target;
        __syncthreads();
    }

    if (tid == 0) {
        const unsigned u = prefix;
        const float med = (u & 0x80000000u) ? __uint_as_float(u ^ 0x80000000u)
                                            : __uint_as_float(~u);
        const float n = (float)DFEAT;
        const float mean = fsum / n;
        const float var = (fss - fsum * fsum / n) / (n - 1.f);
        float* sp = stats + (size_t)row * 10;
        sp[0] = mean;
        sp[1] = sqrtf(var);
        sp[2] = fmn;
        sp[3] = fmx;
        sp[4] = med;
        sp[5] = var;
        sp[6] = sqrtf(fss);
        sp[7] = fl1;
        sp[8] = fpos;
        sp[9] = fneg;
    }
}

// ---------------------------------------------------------------------------
// Kernel 2: cbias[256] = b1 + k_embed @ W1[4096:4160] + pos_enc @ W1[4160:4165]
// ---------------------------------------------------------------------------
__global__ __launch_bounds__(256) void prep_kernel(const int* kp, const int* tp,
                                                   const int* fp, const int* sp,
                                                   const int* msp,
                                                   const float* __restrict__ W1,
                                                   const float* __restrict__ b1,
                                                   float* __restrict__ cbias)
{
    __shared__ float ke[64];
    __shared__ float pe[5];
    const int tid = threadIdx.x;
    if (tid < 32) {
        const float c = (float)(-log(10000.0) / 31.0);   // matches f32(-ln(1e4)/(half-1))
        const float freq = expf((float)tid * c);
        const float e = (float)(*kp) * freq;
        const double ed = (double)e;
        ke[tid]      = (float)sin(ed);
        ke[tid + 32] = (float)cos(ed);
    }
    if (tid == 0) {
        const float tf = (float)(*tp), ff = (float)(*fp);
        pe[0] = (float)sin((double)(0.1f * tf));
        pe[1] = (float)cos((double)(0.1f * tf));
        pe[2] = (float)sin((double)(0.1f * ff));
        pe[3] = (float)cos((double)(0.1f * ff));
        pe[4] = (float)(*sp) / (float)(*msp);
    }
    __syncthreads();
    float acc = b1[tid];
    #pragma unroll 8
    for (int i = 0; i < 64; ++i) acc += ke[i] * W1[(size_t)(4096 + i) * 256 + tid];
    #pragma unroll
    for (int i = 0; i < 5; ++i)  acc += pe[i] * W1[(size_t)(4160 + i) * 256 + tid];
    cbias[tid] = acc;
}

// ---------------------------------------------------------------------------
// Kernel 3: fused MLP. Block = 32 rows x all 256 cols of layer 1, then
// layers 2/3/4 + softmax entirely in-block via LDS.
// ---------------------------------------------------------------------------
__global__ __launch_bounds__(256) void mlp_kernel(
    const float* __restrict__ z, const float* __restrict__ W1,
    const float* __restrict__ W2, const float* __restrict__ b2,
    const float* __restrict__ W3, const float* __restrict__ b3,
    const float* __restrict__ W4, const float* __restrict__ b4,
    const float* __restrict__ stats, const float* __restrict__ cbias,
    float* __restrict__ out)
{
    // phase 1: As[32][32] (1024) + Bs[32][256] (8192)
    // phase 2: Hs[32][257] (8224) + H2[32][129] (4128) + H3[32][65] (2080) = 14432
    __shared__ float smem[14432];
    float* As = smem;                 // [BK][BM]
    float* Bs = smem + 1024;          // [BK][256]
    float* Hs = smem;                 // [32][257]
    float* H2 = smem + 32 * 257;      // [32][129]
    float* H3 = smem + 32 * 257 + 32 * 129;   // [32][65]

    const int tid = threadIdx.x;
    const int ty = tid >> 5;          // 0..7  (4 rows each)
    const int tx = tid & 31;          // 0..31 (8 cols each)
    const int row0 = blockIdx.x * BM;

    float acc[4][8];
    #pragma unroll
    for (int i = 0; i < 4; ++i)
        #pragma unroll
        for (int j = 0; j < 8; ++j) acc[i][j] = 0.f;

    // register prefetch buffers (double-buffer staging without extra LDS)
    const int sm = tid >> 3;               // 0..31 : A row within tile
    const int skq = (tid & 7) * 4;         // 0..28 : A k-quad
    float4 pa;
    float4 pb[8];

    {   // prefetch tile 0
        pa = *reinterpret_cast<const float4*>(z + (size_t)(row0 + sm) * DFEAT + skq);
        #pragma unroll
        for (int j = 0; j < 8; ++j) {
            const int f4i = j * 256 + tid;
            const int kk = f4i >> 6;
            const int c4 = f4i & 63;
            pb[j] = *reinterpret_cast<const float4*>(W1 + (size_t)kk * 256 + c4 * 4);
        }
    }

    for (int k0 = 0; k0 < DFEAT; k0 += BK) {
        __syncthreads();   // previous compute done -> safe to overwrite LDS
        // commit prefetched regs to LDS
        As[(skq + 0) * BM + sm] = pa.x;
        As[(skq + 1) * BM + sm] = pa.y;
        As[(skq + 2) * BM + sm] = pa.z;
        As[(skq + 3) * BM + sm] = pa.w;
        #pragma unroll
        for (int j = 0; j < 8; ++j) {
            const int f4i = j * 256 + tid;
            const int kk = f4i >> 6;
            const int c4 = f4i & 63;
            *reinterpret_cast<float4*>(Bs + kk * 256 + c4 * 4) = pb[j];
        }
        __syncthreads();

        // issue next tile's global loads (overlap with compute below)
        const int kn = k0 + BK;
        if (kn < DFEAT) {
            pa = *reinterpret_cast<const float4*>(z + (size_t)(row0 + sm) * DFEAT + kn + skq);
            #pragma unroll
            for (int j = 0; j < 8; ++j) {
                const int f4i = j * 256 + tid;
                const int kk = f4i >> 6;
                const int c4 = f4i & 63;
                pb[j] = *reinterpret_cast<const float4*>(W1 + (size_t)(kn + kk) * 256 + c4 * 4);
            }
        }

        #pragma unroll 8
        for (int kk = 0; kk < BK; ++kk) {
            const float4 a  = *reinterpret_cast<const float4*>(As + kk * BM + ty * 4);
            const float4 b0 = *reinterpret_cast<const float4*>(Bs + kk * 256 + tx * 8);
            const float4 b1v = *reinterpret_cast<const float4*>(Bs + kk * 256 + tx * 8 + 4);
            const float av[4] = {a.x, a.y, a.z, a.w};
            const float bv[8] = {b0.x, b0.y, b0.z, b0.w, b1v.x, b1v.y, b1v.z, b1v.w};
            #pragma unroll
            for (int i = 0; i < 4; ++i)
                #pragma unroll
                for (int j = 0; j < 8; ++j)
                    acc[i][j] += av[i] * bv[j];
        }
    }
    __syncthreads();   // done reading As/Bs; smem is reused as Hs/H2/H3

    // epilogue of layer 1: + stats @ W1s + cbias, ReLU -> Hs
    #pragma unroll
    for (int i = 0; i < 4; ++i) {
        const int r = ty * 4 + i;
        const float* st = stats + (size_t)(row0 + r) * 10;
        float s10[10];
        #pragma unroll
        for (int j = 0; j < 10; ++j) s10[j] = st[j];
        #pragma unroll
        for (int c = 0; c < 8; ++c) {
            const int col = tx * 8 + c;
            float h = acc[i][c] + cbias[col];
            #pragma unroll
            for (int j = 0; j < 10; ++j)
                h += s10[j] * W1[(size_t)(4165 + j) * 256 + col];
            Hs[r * 257 + col] = fmaxf(h, 0.f);
        }
    }
    __syncthreads();

    // layer 2: [32x256] @ [256x128] -> H2
    {
        const int r = tid >> 3;
        const int c0 = (tid & 7) * 16;
        float a2[16];
        #pragma unroll
        for (int i = 0; i < 16; ++i) a2[i] = b2[c0 + i];
        for (int k = 0; k < 256; ++k) {
            const float hv = Hs[r * 257 + k];
            const float4 w0 = *reinterpret_cast<const float4*>(W2 + (size_t)k * 128 + c0);
            const float4 w1 = *reinterpret_cast<const float4*>(W2 + (size_t)k * 128 + c0 + 4);
            const float4 w2 = *reinterpret_cast<const float4*>(W2 + (size_t)k * 128 + c0 + 8);
            const float4 w3 = *reinterpret_cast<const float4*>(W2 + (size_t)k * 128 + c0 + 12);
            const float wv[16] = {w0.x,w0.y,w0.z,w0.w, w1.x,w1.y,w1.z,w1.w,
                                  w2.x,w2.y,w2.z,w2.w, w3.x,w3.y,w3.z,w3.w};
            #pragma unroll
            for (int i = 0; i < 16; ++i) a2[i] += hv * wv[i];
        }
        #pragma unroll
        for (int i = 0; i < 16; ++i)
            H2[r * 129 + c0 + i] = fmaxf(a2[i], 0.f);
    }
    __syncthreads();

    // layer 3: [32x128] @ [128x64] -> H3
    {
        const int r = tid >> 3;
        const int c0 = (tid & 7) * 8;
        float a3[8];
        #pragma unroll
        for (int i = 0; i < 8; ++i) a3[i] = b3[c0 + i];
        for (int k = 0; k < 128; ++k) {
            const float hv = H2[r * 129 + k];
            const float4 w0 = *reinterpret_cast<const float4*>(W3 + (size_t)k * 64 + c0);
            const float4 w1 = *reinterpret_cast<const float4*>(W3 + (size_t)k * 64 + c0 + 4);
            const float wv[8] = {w0.x,w0.y,w0.z,w0.w, w1.x,w1.y,w1.z,w1.w};
            #pragma unroll
            for (int i = 0; i < 8; ++i) a3[i] += hv * wv[i];
        }
        #pragma unroll
        for (int i = 0; i < 8; ++i)
            H3[r * 65 + c0 + i] = fmaxf(a3[i], 0.f);
    }
    __syncthreads();

    // layer 4 + softmax: one thread per row
    if (tid < BM) {
        const int r = tid;
        float lg[5];
        #pragma unroll
        for (int j = 0; j < 5; ++j) lg[j] = b4[j];
        for (int k = 0; k < 64; ++k) {
            const float hv = H3[r * 65 + k];
            #pragma unroll
            for (int j = 0; j < 5; ++j) lg[j] += hv * W4[k * 5 + j];
        }
        float m = lg[0];
        #pragma unroll
        for (int j = 1; j < 5; ++j) m = fmaxf(m, lg[j]);
        float e[5], s = 0.f;
        #pragma unroll
        for (int j = 0; j < 5; ++j) { e[j] = expf(lg[j] - m); s += e[j]; }
        float* op = out + (size_t)(row0 + r) * 5;
        #pragma unroll
        for (int j = 0; j < 5; ++j) op[j] = e[j] / s;
    }
}

// ---------------------------------------------------------------------------
extern "C" void kernel_launch(void* const* d_in, const int* in_sizes, int n_in,
                              void* d_out, int out_size, void* d_ws, size_t ws_size,
                              hipStream_t stream)
{
    const float* z   = (const float*)d_in[0];
    const int*   kp  = (const int*)d_in[1];
    const int*   tp  = (const int*)d_in[2];
    const int*   fp  = (const int*)d_in[3];
    const int*   sp  = (const int*)d_in[4];
    const int*   msp = (const int*)d_in[5];
    const float* W1  = (const float*)d_in[6];
    const float* b1  = (const float*)d_in[7];
    const float* W2  = (const float*)d_in[8];
    const float* b2  = (const float*)d_in[9];
    const float* W3  = (const float*)d_in[10];
    const float* b3  = (const float*)d_in[11];
    const float* W4  = (const float*)d_in[12];
    const float* b4  = (const float*)d_in[13];
    float* out = (float*)d_out;

    const int B = in_sizes[0] / DFEAT;            // 8192
    float* ws_stats = (float*)d_ws;               // [B][10]
    float* ws_cbias = ws_stats + (size_t)B * 10;  // [256]

    hipLaunchKernelGGL(stats_kernel, dim3(B), dim3(256), 0, stream, z, ws_stats);
    hipLaunchKernelGGL(prep_kernel, dim3(1), dim3(256), 0, stream,
                       kp, tp, fp, sp, msp, W1, b1, ws_cbias);
    hipLaunchKernelGGL(mlp_kernel, dim3(B / BM), dim3(256), 0, stream,
                       z, W1, W2, b2, W3, b3, W4, b4, ws_stats, ws_cbias, out);
}

// Round 3
// 519.423 us; speedup vs baseline: 1.7183x; 1.7183x over previous
//
#include <hip/hip_runtime.h>
#include <math.h>
#include <stdint.h>

#define DFEAT 4096
#define AS1 __attribute__((address_space(1)))
#define AS3 __attribute__((address_space(3)))

typedef _Float16 f16x8 __attribute__((ext_vector_type(8)));
typedef float f32x4 __attribute__((ext_vector_type(4)));

// ---------------------------------------------------------------------------
// Kernel 1: per-row stats, one WAVE per row (no barriers, no atomics).
// Median via 32-step binary search on sign-flipped uint keys held in registers.
// stats[r][0..9] = mean, std(ddof=1), min, max, lower-median, var, l2, l1, pos, neg
// ---------------------------------------------------------------------------
__global__ __launch_bounds__(256, 4) void stats_kernel(const float* __restrict__ z,
                                                       float* __restrict__ stats)
{
    const int lane = threadIdx.x & 63;
    const int wv   = threadIdx.x >> 6;
    const int row  = blockIdx.x * 4 + wv;
    const float* zr = z + (size_t)row * DFEAT;

    unsigned keys[64];
    float sum = 0.f, ss = 0.f, l1 = 0.f;
    float mn = INFINITY, mx = -INFINITY;
    int pos = 0, neg = 0;

    #pragma unroll
    for (int j = 0; j < 16; ++j) {
        float4 v = reinterpret_cast<const float4*>(zr)[lane + j * 64];
        float vv[4] = {v.x, v.y, v.z, v.w};
        #pragma unroll
        for (int e = 0; e < 4; ++e) {
            float x = vv[e];
            sum += x; ss += x * x; l1 += fabsf(x);
            mn = fminf(mn, x); mx = fmaxf(mx, x);
            pos += (x > 0.f) ? 1 : 0;
            neg += (x < 0.f) ? 1 : 0;
            unsigned u = __float_as_uint(x);
            keys[j * 4 + e] = (u & 0x80000000u) ? ~u : (u | 0x80000000u);
        }
    }

    // wave butterfly reduction for the 7 streaming stats
    #pragma unroll
    for (int off = 1; off < 64; off <<= 1) {
        sum += __shfl_xor(sum, off);
        ss  += __shfl_xor(ss,  off);
        l1  += __shfl_xor(l1,  off);
        mn = fminf(mn, __shfl_xor(mn, off));
        mx = fmaxf(mx, __shfl_xor(mx, off));
        pos += __shfl_xor(pos, off);
        neg += __shfl_xor(neg, off);
    }

    // median: largest v with count(keys < v) <= 2047  ==  key of rank 2047
    unsigned lo = 0u;
    const int t = (DFEAT - 1) / 2;   // 2047
    #pragma unroll 1
    for (int b = 31; b >= 0; --b) {
        const unsigned mid = lo | (1u << b);
        int cnt = 0;
        #pragma unroll
        for (int i = 0; i < 64; ++i) cnt += (keys[i] < mid) ? 1 : 0;
        #pragma unroll
        for (int off = 1; off < 64; off <<= 1) cnt += __shfl_xor(cnt, off);
        if (cnt <= t) lo = mid;
    }

    if (lane == 0) {
        const float med = (lo & 0x80000000u) ? __uint_as_float(lo ^ 0x80000000u)
                                             : __uint_as_float(~lo);
        const float n = (float)DFEAT;
        const float mean = sum / n;
        const float var = (ss - sum * sum / n) / (n - 1.f);
        float* sp = stats + (size_t)row * 10;
        sp[0] = mean;
        sp[1] = sqrtf(var);
        sp[2] = mn;
        sp[3] = mx;
        sp[4] = med;
        sp[5] = var;
        sp[6] = sqrtf(ss);
        sp[7] = l1;
        sp[8] = (float)pos;
        sp[9] = (float)neg;
    }
}

// ---------------------------------------------------------------------------
// Kernel 2: split W1[0:4096][256] into f16 (high, residual*2048) pre-swizzled
// LDS-image chunks: img[k0/32][32 KiB] ; within a chunk:
//   Bh granule: byte = col*64 + ((g ^ ((col>>1)&3))<<4)  holds B[k0+g*8 .. +7][col]
//   Bl section at +16384 (same layout)
// ---------------------------------------------------------------------------
__global__ __launch_bounds__(256) void split_kernel(const float* __restrict__ W1,
                                                    char* __restrict__ img)
{
    const int c   = blockIdx.x;     // k-chunk 0..127
    const int col = threadIdx.x;    // 0..255
    const int k0  = c * 32;
    _Float16 h16[32], l16[32];
    #pragma unroll
    for (int kk = 0; kk < 32; ++kk) {
        float w = W1[(size_t)(k0 + kk) * 256 + col];
        _Float16 h = (_Float16)w;
        float rr = (w - (float)h) * 2048.f;
        h16[kk] = h;
        l16[kk] = (_Float16)rr;
    }
    char* base = img + (size_t)c * 32768;
    const int sw = (col >> 1) & 3;
    #pragma unroll
    for (int g = 0; g < 4; ++g) {
        f16x8 vh, vl;
        #pragma unroll
        for (int j = 0; j < 8; ++j) { vh[j] = h16[g * 8 + j]; vl[j] = l16[g * 8 + j]; }
        const int off = col * 64 + ((g ^ sw) << 4);
        *reinterpret_cast<f16x8*>(base + off)         = vh;
        *reinterpret_cast<f16x8*>(base + 16384 + off) = vl;
    }
}

// ---------------------------------------------------------------------------
// Kernel 3: cbias[256] = b1 + k_embed @ W1[4096:4160] + pos_enc @ W1[4160:4165]
// ---------------------------------------------------------------------------
__global__ __launch_bounds__(256) void prep_kernel(const int* kp, const int* tp,
                                                   const int* fp, const int* sp,
                                                   const int* msp,
                                                   const float* __restrict__ W1,
                                                   const float* __restrict__ b1,
                                                   float* __restrict__ cbias)
{
    __shared__ float ke[64];
    __shared__ float pe[5];
    const int tid = threadIdx.x;
    if (tid < 32) {
        const float c = (float)(-log(10000.0) / 31.0);
        const float freq = expf((float)tid * c);
        const float e = (float)(*kp) * freq;
        const double ed = (double)e;
        ke[tid]      = (float)sin(ed);
        ke[tid + 32] = (float)cos(ed);
    }
    if (tid == 0) {
        const float tf = (float)(*tp), ff = (float)(*fp);
        pe[0] = (float)sin((double)(0.1f * tf));
        pe[1] = (float)cos((double)(0.1f * tf));
        pe[2] = (float)sin((double)(0.1f * ff));
        pe[3] = (float)cos((double)(0.1f * ff));
        pe[4] = (float)(*sp) / (float)(*msp);
    }
    __syncthreads();
    float acc = b1[tid];
    #pragma unroll 8
    for (int i = 0; i < 64; ++i) acc += ke[i] * W1[(size_t)(4096 + i) * 256 + tid];
    #pragma unroll
    for (int i = 0; i < 5; ++i)  acc += pe[i] * W1[(size_t)(4160 + i) * 256 + tid];
    cbias[tid] = acc;
}

// ---------------------------------------------------------------------------
// Kernel 4: fused MLP. Layer 1 via f16 MFMA split-precision (3 products),
// B staged by identity-copy global_load_lds from pre-swizzled images,
// A (z) loaded straight to registers. Epilogue: stats rank-10 update + bias
// + ReLU, then layers 2/3/4 + softmax in-block.
// Block = 256 thr (4 waves, 2x2 over 32 rows x 256 cols). Grid = 256.
// ---------------------------------------------------------------------------
__global__ __launch_bounds__(256, 1) void mlp_kernel(
    const float* __restrict__ z, const char* __restrict__ img,
    const float* __restrict__ W1, const float* __restrict__ W2,
    const float* __restrict__ b2, const float* __restrict__ W3,
    const float* __restrict__ b3, const float* __restrict__ W4,
    const float* __restrict__ b4, const float* __restrict__ stats,
    const float* __restrict__ cbias, float* __restrict__ out)
{
    __shared__ char lds[65536];   // 2 x 32 KiB B double-buffer; reused by epilogue

    const int tid  = threadIdx.x;
    const int wv   = tid >> 6;           // 0..3
    const int r    = wv >> 1;            // row-half of the 2x2 wave grid
    const int cg   = wv & 1;             // col-half
    const int lane = tid & 63;
    const int q    = lane & 15;
    const int g    = lane >> 4;
    const int row0 = blockIdx.x * 32;

    f32x4 acc0[8], acc1[8];
    #pragma unroll
    for (int f = 0; f < 8; ++f) {
        acc0[f] = (f32x4){0.f, 0.f, 0.f, 0.f};
        acc1[f] = (f32x4){0.f, 0.f, 0.f, 0.f};
    }

    // A: lane (q,g) of wave-row r always reads row (row0+16r+q), k = 32t + 8g + j
    const float* arow = z + (size_t)(row0 + 16 * r + q) * DFEAT + g * 8;
    const int sw = (q >> 1) & 3;

    // stage macro: identity copy of a 32 KiB chunk image into LDS buffer
#define STAGE_B(T, DST) do {                                                   \
        const char* gsrc_ = img + (size_t)(T) * 32768 + wv * 8192 + lane * 16; \
        char* ldst_ = (DST) + wv * 8192;                                       \
        _Pragma("unroll")                                                      \
        for (int i_ = 0; i_ < 8; ++i_) {                                       \
            __builtin_amdgcn_global_load_lds(                                  \
                (const AS1 void*)(gsrc_ + i_ * 1024),                          \
                (AS3 void*)(ldst_ + i_ * 1024), 16, 0, 0);                     \
        }                                                                      \
    } while (0)

    float af[8];
    {   // prologue: stage chunk 0, load A chunk 0
        STAGE_B(0, lds);
        float4 v0 = *reinterpret_cast<const float4*>(arow);
        float4 v1 = *reinterpret_cast<const float4*>(arow + 4);
        af[0] = v0.x; af[1] = v0.y; af[2] = v0.z; af[3] = v0.w;
        af[4] = v1.x; af[5] = v1.y; af[6] = v1.z; af[7] = v1.w;
    }
    __syncthreads();

    for (int tt = 0; tt < 128; ++tt) {
        char* buf  = lds + ((tt & 1) << 15);
        char* nbuf = lds + (((tt + 1) & 1) << 15);

        // issue next-tile staging first (overlaps with compute below)
        if (tt + 1 < 128) STAGE_B(tt + 1, nbuf);

        // convert current A regs to (high, residual*2048) f16 fragments
        f16x8 ah, al;
        #pragma unroll
        for (int j = 0; j < 8; ++j) {
            _Float16 h = (_Float16)af[j];
            ah[j] = h;
            al[j] = (_Float16)((af[j] - (float)h) * 2048.f);
        }

        // issue next-tile A loads (af dead after conversion)
        if (tt + 1 < 128) {
            const float* an = arow + (tt + 1) * 32;
            float4 v0 = *reinterpret_cast<const float4*>(an);
            float4 v1 = *reinterpret_cast<const float4*>(an + 4);
            af[0] = v0.x; af[1] = v0.y; af[2] = v0.z; af[3] = v0.w;
            af[4] = v1.x; af[5] = v1.y; af[6] = v1.z; af[7] = v1.w;
        }

        // 8 col-fragments x 3 MFMA
        #pragma unroll
        for (int f = 0; f < 8; ++f) {
            const int colf = 128 * cg + 16 * f + q;
            const int off  = colf * 64 + ((g ^ sw) << 4);
            f16x8 bh = *reinterpret_cast<const f16x8*>(buf + off);
            f16x8 bl = *reinterpret_cast<const f16x8*>(buf + 16384 + off);
            acc0[f] = __builtin_amdgcn_mfma_f32_16x16x32_f16(ah, bh, acc0[f], 0, 0, 0);
            acc1[f] = __builtin_amdgcn_mfma_f32_16x16x32_f16(ah, bl, acc1[f], 0, 0, 0);
            acc1[f] = __builtin_amdgcn_mfma_f32_16x16x32_f16(al, bh, acc1[f], 0, 0, 0);
        }
        __syncthreads();
    }

    // ---- epilogue ----
    // LDS reuse: Hs[32][257] @0 (32896B); W1s_s @40000 (10x256 f32);
    // stats_s @50240 (32x10); cb_s @51520 (256); then H2 @40000, H3 @56512.
    float* W1s_s   = reinterpret_cast<float*>(lds + 40000);
    float* stats_s = reinterpret_cast<float*>(lds + 50240);
    float* cb_s    = reinterpret_cast<float*>(lds + 51520);
    float* Hs      = reinterpret_cast<float*>(lds);

    for (int i = tid; i < 2560; i += 256) {
        const int s = i >> 8, cc = i & 255;
        W1s_s[i] = W1[(size_t)(4165 + s) * 256 + cc];
    }
    for (int i = tid; i < 320; i += 256)
        stats_s[i] = stats[(size_t)row0 * 10 + i];
    cb_s[tid] = cbias[tid];
    __syncthreads();

    #pragma unroll
    for (int j = 0; j < 4; ++j) {
        const int m = g * 4 + j;        // C/D layout: row=(lane>>4)*4+j, col=lane&15
        const int grow = 16 * r + m;
        float s10[10];
        #pragma unroll
        for (int s = 0; s < 10; ++s) s10[s] = stats_s[grow * 10 + s];
        #pragma unroll
        for (int f = 0; f < 8; ++f) {
            const int colf = 128 * cg + 16 * f + q;
            float h = acc0[f][j] + acc1[f][j] * (1.f / 2048.f) + cb_s[colf];
            #pragma unroll
            for (int s = 0; s < 10; ++s) h += s10[s] * W1s_s[s * 256 + colf];
            Hs[grow * 257 + colf] = fmaxf(h, 0.f);
        }
    }
    __syncthreads();

    // layer 2: [32x256] @ [256x128] -> H2
    float* H2 = reinterpret_cast<float*>(lds + 40000);   // [32][129]
    {
        const int rr = tid >> 3;
        const int c0 = (tid & 7) * 16;
        float a2[16];
        #pragma unroll
        for (int i = 0; i < 16; ++i) a2[i] = b2[c0 + i];
        for (int k = 0; k < 256; ++k) {
            const float hv = Hs[rr * 257 + k];
            const float4 w0 = *reinterpret_cast<const float4*>(W2 + (size_t)k * 128 + c0);
            const float4 w1 = *reinterpret_cast<const float4*>(W2 + (size_t)k * 128 + c0 + 4);
            const float4 w2 = *reinterpret_cast<const float4*>(W2 + (size_t)k * 128 + c0 + 8);
            const float4 w3 = *reinterpret_cast<const float4*>(W2 + (size_t)k * 128 + c0 + 12);
            const float wvv[16] = {w0.x,w0.y,w0.z,w0.w, w1.x,w1.y,w1.z,w1.w,
                                   w2.x,w2.y,w2.z,w2.w, w3.x,w3.y,w3.z,w3.w};
            #pragma unroll
            for (int i = 0; i < 16; ++i) a2[i] += hv * wvv[i];
        }
        __syncthreads();   // all Hs/W1s-region reads done before H2 overwrites it
        #pragma unroll
        for (int i = 0; i < 16; ++i)
            H2[rr * 129 + c0 + i] = fmaxf(a2[i], 0.f);
    }
    __syncthreads();

    // layer 3: [32x128] @ [128x64] -> H3
    float* H3 = reinterpret_cast<float*>(lds + 56512);   // [32][65]
    {
        const int rr = tid >> 3;
        const int c0 = (tid & 7) * 8;
        float a3[8];
        #pragma unroll
        for (int i = 0; i < 8; ++i) a3[i] = b3[c0 + i];
        for (int k = 0; k < 128; ++k) {
            const float hv = H2[rr * 129 + k];
            const float4 w0 = *reinterpret_cast<const float4*>(W3 + (size_t)k * 64 + c0);
            const float4 w1 = *reinterpret_cast<const float4*>(W3 + (size_t)k * 64 + c0 + 4);
            const float wvv[8] = {w0.x,w0.y,w0.z,w0.w, w1.x,w1.y,w1.z,w1.w};
            #pragma unroll
            for (int i = 0; i < 8; ++i) a3[i] += hv * wvv[i];
        }
        #pragma unroll
        for (int i = 0; i < 8; ++i)
            H3[rr * 65 + c0 + i] = fmaxf(a3[i], 0.f);
    }
    __syncthreads();

    // layer 4 + softmax: one thread per row
    if (tid < 32) {
        const int rr = tid;
        float lg[5];
        #pragma unroll
        for (int j = 0; j < 5; ++j) lg[j] = b4[j];
        for (int k = 0; k < 64; ++k) {
            const float hv = H3[rr * 65 + k];
            #pragma unroll
            for (int j = 0; j < 5; ++j) lg[j] += hv * W4[k * 5 + j];
        }
        float m = lg[0];
        #pragma unroll
        for (int j = 1; j < 5; ++j) m = fmaxf(m, lg[j]);
        float e[5], s = 0.f;
        #pragma unroll
        for (int j = 0; j < 5; ++j) { e[j] = expf(lg[j] - m); s += e[j]; }
        float* op = out + (size_t)(row0 + rr) * 5;
        #pragma unroll
        for (int j = 0; j < 5; ++j) op[j] = e[j] / s;
    }
#undef STAGE_B
}

// ---------------------------------------------------------------------------
extern "C" void kernel_launch(void* const* d_in, const int* in_sizes, int n_in,
                              void* d_out, int out_size, void* d_ws, size_t ws_size,
                              hipStream_t stream)
{
    const float* z   = (const float*)d_in[0];
    const int*   kp  = (const int*)d_in[1];
    const int*   tp  = (const int*)d_in[2];
    const int*   fp  = (const int*)d_in[3];
    const int*   sp  = (const int*)d_in[4];
    const int*   msp = (const int*)d_in[5];
    const float* W1  = (const float*)d_in[6];
    const float* b1  = (const float*)d_in[7];
    const float* W2  = (const float*)d_in[8];
    const float* b2  = (const float*)d_in[9];
    const float* W3  = (const float*)d_in[10];
    const float* b3  = (const float*)d_in[11];
    const float* W4  = (const float*)d_in[12];
    const float* b4  = (const float*)d_in[13];
    float* out = (float*)d_out;

    const int B = in_sizes[0] / DFEAT;             // 8192
    float* ws_stats = (float*)d_ws;                // [B][10]       (B*40 bytes)
    float* ws_cbias = ws_stats + (size_t)B * 10;   // [256]
    char*  ws_img   = (char*)(ws_cbias + 256);     // 128 x 32 KiB = 4 MiB

    hipLaunchKernelGGL(stats_kernel, dim3(B / 4), dim3(256), 0, stream, z, ws_stats);
    hipLaunchKernelGGL(split_kernel, dim3(128), dim3(256), 0, stream, W1, ws_img);
    hipLaunchKernelGGL(prep_kernel, dim3(1), dim3(256), 0, stream,
                       kp, tp, fp, sp, msp, W1, b1, ws_cbias);
    hipLaunchKernelGGL(mlp_kernel, dim3(B / 32), dim3(256), 0, stream,
                       z, ws_img, W1, W2, b2, W3, b3, W4, b4,
                       ws_stats, ws_cbias, out);
}

// Round 5
// 504.487 us; speedup vs baseline: 1.7692x; 1.0296x over previous
//
#include <hip/hip_runtime.h>
#include <math.h>
#include <stdint.h>

#define DFEAT 4096
#define AS1 __attribute__((address_space(1)))
#define AS3 __attribute__((address_space(3)))

typedef _Float16 f16x8 __attribute__((ext_vector_type(8)));
typedef float f32x4 __attribute__((ext_vector_type(4)));

// ---------------------------------------------------------------------------
// Kernel 1: per-row stats, one BLOCK per row. 16 keys/lane (no spill risk).
// Median via 32-step binary search; cross-wave combine through 4-entry LDS.
// stats[r][0..9] = mean, std(ddof=1), min, max, lower-median, var, l2, l1, pos, neg
// ---------------------------------------------------------------------------
__global__ __launch_bounds__(256) void stats_kernel(const float* __restrict__ z,
                                                    float* __restrict__ stats)
{
    const int row  = blockIdx.x;
    const int tid  = threadIdx.x;
    const int lane = tid & 63;
    const int wv   = tid >> 6;
    __shared__ float wred[4][7];
    __shared__ int   wcnt[4];

    const float* zr = z + (size_t)row * DFEAT;

    unsigned keys[16];
    float sum = 0.f, ss = 0.f, l1 = 0.f;
    float mn = INFINITY, mx = -INFINITY;
    int pos = 0, neg = 0;

    #pragma unroll
    for (int j = 0; j < 4; ++j) {
        float4 v = reinterpret_cast<const float4*>(zr)[tid + j * 256];
        float vv[4] = {v.x, v.y, v.z, v.w};
        #pragma unroll
        for (int e = 0; e < 4; ++e) {
            float x = vv[e];
            sum += x; ss += x * x; l1 += fabsf(x);
            mn = fminf(mn, x); mx = fmaxf(mx, x);
            pos += (x > 0.f) ? 1 : 0;
            neg += (x < 0.f) ? 1 : 0;
            unsigned u = __float_as_uint(x);
            keys[j * 4 + e] = (u & 0x80000000u) ? ~u : (u | 0x80000000u);
        }
    }

    // wave butterfly reduction for the 7 streaming stats
    #pragma unroll
    for (int off = 1; off < 64; off <<= 1) {
        sum += __shfl_xor(sum, off);
        ss  += __shfl_xor(ss,  off);
        l1  += __shfl_xor(l1,  off);
        mn = fminf(mn, __shfl_xor(mn, off));
        mx = fmaxf(mx, __shfl_xor(mx, off));
        pos += __shfl_xor(pos, off);
        neg += __shfl_xor(neg, off);
    }
    if (lane == 0) {
        wred[wv][0] = sum; wred[wv][1] = ss; wred[wv][2] = l1;
        wred[wv][3] = mn;  wred[wv][4] = mx;
        wred[wv][5] = (float)pos; wred[wv][6] = (float)neg;
    }
    __syncthreads();

    // median: rank-2047 key via bit-descent; count combined across 4 waves in LDS
    unsigned lo = 0u;
    #pragma unroll 1
    for (int b = 31; b >= 0; --b) {
        const unsigned mid = lo | (1u << b);
        int c = 0;
        #pragma unroll
        for (int i = 0; i < 16; ++i) c += (keys[i] < mid) ? 1 : 0;
        #pragma unroll
        for (int off = 1; off < 64; off <<= 1) c += __shfl_xor(c, off);
        if (lane == 0) wcnt[wv] = c;
        __syncthreads();
        const int tot = wcnt[0] + wcnt[1] + wcnt[2] + wcnt[3];
        if (tot <= 2047) lo = mid;           // uniform decision across block
        __syncthreads();
    }

    if (tid == 0) {
        float fsum = 0.f, fss = 0.f, fl1 = 0.f, fpos = 0.f, fneg = 0.f;
        float fmn = INFINITY, fmx = -INFINITY;
        #pragma unroll
        for (int w = 0; w < 4; ++w) {
            fsum += wred[w][0]; fss += wred[w][1]; fl1 += wred[w][2];
            fmn = fminf(fmn, wred[w][3]); fmx = fmaxf(fmx, wred[w][4]);
            fpos += wred[w][5]; fneg += wred[w][6];
        }
        const float med = (lo & 0x80000000u) ? __uint_as_float(lo ^ 0x80000000u)
                                             : __uint_as_float(~lo);
        const float n = (float)DFEAT;
        const float mean = fsum / n;
        const float var = (fss - fsum * fsum / n) / (n - 1.f);
        float* sp = stats + (size_t)row * 10;
        sp[0] = mean;
        sp[1] = sqrtf(var);
        sp[2] = fmn;
        sp[3] = fmx;
        sp[4] = med;
        sp[5] = var;
        sp[6] = sqrtf(fss);
        sp[7] = fl1;
        sp[8] = fpos;
        sp[9] = fneg;
    }
}

// ---------------------------------------------------------------------------
// Kernel 2: split W1[0:4096][256] into f16 (high, residual*2048) pre-swizzled
// LDS-image chunks: img[k0/32][32 KiB]; within a chunk:
//   Bh granule: byte = col*64 + ((g ^ ((col>>1)&3))<<4)  holds B[k0+g*8 .. +7][col]
//   Bl section at +16384 (same layout)
// ---------------------------------------------------------------------------
__global__ __launch_bounds__(256) void split_kernel(const float* __restrict__ W1,
                                                    char* __restrict__ img)
{
    const int c   = blockIdx.x;     // k-chunk 0..127
    const int col = threadIdx.x;    // 0..255
    const int k0  = c * 32;
    _Float16 h16[32], l16[32];
    #pragma unroll
    for (int kk = 0; kk < 32; ++kk) {
        float w = W1[(size_t)(k0 + kk) * 256 + col];
        _Float16 h = (_Float16)w;
        float rr = (w - (float)h) * 2048.f;
        h16[kk] = h;
        l16[kk] = (_Float16)rr;
    }
    char* base = img + (size_t)c * 32768;
    const int sw = (col >> 1) & 3;
    #pragma unroll
    for (int g = 0; g < 4; ++g) {
        f16x8 vh, vl;
        #pragma unroll
        for (int j = 0; j < 8; ++j) { vh[j] = h16[g * 8 + j]; vl[j] = l16[g * 8 + j]; }
        const int off = col * 64 + ((g ^ sw) << 4);
        *reinterpret_cast<f16x8*>(base + off)         = vh;
        *reinterpret_cast<f16x8*>(base + 16384 + off) = vl;
    }
}

// ---------------------------------------------------------------------------
// Kernel 3: cbias[256] = b1 + k_embed @ W1[4096:4160] + pos_enc @ W1[4160:4165]
// ---------------------------------------------------------------------------
__global__ __launch_bounds__(256) void prep_kernel(const int* kp, const int* tp,
                                                   const int* fp, const int* sp,
                                                   const int* msp,
                                                   const float* __restrict__ W1,
                                                   const float* __restrict__ b1,
                                                   float* __restrict__ cbias)
{
    __shared__ float ke[64];
    __shared__ float pe[5];
    const int tid = threadIdx.x;
    if (tid < 32) {
        const float c = (float)(-log(10000.0) / 31.0);
        const float freq = expf((float)tid * c);
        const float e = (float)(*kp) * freq;
        const double ed = (double)e;
        ke[tid]      = (float)sin(ed);
        ke[tid + 32] = (float)cos(ed);
    }
    if (tid == 0) {
        const float tf = (float)(*tp), ff = (float)(*fp);
        pe[0] = (float)sin((double)(0.1f * tf));
        pe[1] = (float)cos((double)(0.1f * tf));
        pe[2] = (float)sin((double)(0.1f * ff));
        pe[3] = (float)cos((double)(0.1f * ff));
        pe[4] = (float)(*sp) / (float)(*msp);
    }
    __syncthreads();
    float acc = b1[tid];
    #pragma unroll 8
    for (int i = 0; i < 64; ++i) acc += ke[i] * W1[(size_t)(4096 + i) * 256 + tid];
    #pragma unroll
    for (int i = 0; i < 5; ++i)  acc += pe[i] * W1[(size_t)(4160 + i) * 256 + tid];
    cbias[tid] = acc;
}

// ---------------------------------------------------------------------------
// Kernel 4: fused MLP. Layer 1 via f16 MFMA split-precision (3 products).
// Ring-4 LDS buffer (128 KiB), counted s_waitcnt vmcnt(10) + raw s_barrier:
// 3 chunk-stages stay in flight across barriers (T3/T4). A-loads prefetched
// 2 chunks ahead in named register buffers. Tail handled by mod-128 wrap so
// the vmcnt retirement invariant is uniform.
// ---------------------------------------------------------------------------
__global__ __launch_bounds__(256, 1) void mlp_kernel(
    const float* __restrict__ z, const char* __restrict__ img,
    const float* __restrict__ W1, const float* __restrict__ W2,
    const float* __restrict__ b2, const float* __restrict__ W3,
    const float* __restrict__ b3, const float* __restrict__ W4,
    const float* __restrict__ b4, const float* __restrict__ stats,
    const float* __restrict__ cbias, float* __restrict__ out)
{
    __shared__ char lds[131072];   // 4 x 32 KiB ring; reused by epilogue

    const int tid  = threadIdx.x;
    const int wv   = tid >> 6;           // 0..3
    const int r    = wv >> 1;            // row-half of the 2x2 wave grid
    const int cg   = wv & 1;             // col-half
    const int lane = tid & 63;
    const int q    = lane & 15;
    const int g    = lane >> 4;
    const int row0 = blockIdx.x * 32;

    f32x4 acc0[8], acc1[8];
    #pragma unroll
    for (int f = 0; f < 8; ++f) {
        acc0[f] = (f32x4){0.f, 0.f, 0.f, 0.f};
        acc1[f] = (f32x4){0.f, 0.f, 0.f, 0.f};
    }

    // A: lane (q,g) of wave-row r reads row (row0+16r+q), k = 32t + 8g + j
    const float* arow = z + (size_t)(row0 + 16 * r + q) * DFEAT + g * 8;
    const int sw = (q >> 1) & 3;

    // stage: identity copy of chunk image (8 x 16B/lane) into ring slot
    auto STAGE = [&](int chunk, int slot) {
        const char* gsrc = img + (size_t)chunk * 32768 + wv * 8192 + lane * 16;
        char* ldst = lds + (slot << 15) + wv * 8192;
        #pragma unroll
        for (int i = 0; i < 8; ++i)
            __builtin_amdgcn_global_load_lds((const AS1 void*)(gsrc + i * 1024),
                                             (AS3 void*)(ldst + i * 1024), 16, 0, 0);
    };
    auto LOADA = [&](int chunk, float4& v0, float4& v1) {
        const float* an = arow + chunk * 32;
        v0 = *reinterpret_cast<const float4*>(an);
        v1 = *reinterpret_cast<const float4*>(an + 4);
    };

    float4 aA0, aA1, aB0, aB1;
    // prologue — issue order fixes the vmcnt ledger:
    // [stage0(8), stage1(8), loadA0(2), stage2(8), loadA1(2)] = 28 outstanding
    STAGE(0, 0);
    STAGE(1, 1);
    LOADA(0, aA0, aA1);
    STAGE(2, 2);
    LOADA(1, aB0, aB1);

    // per-chunk: wait vmcnt<=10  ==> in-order retirement covers stage(t) and
    // loadA(t), leaving exactly [stage(t+2)(8), loadA(t+1)(2)] in flight.
#define CHUNK_BODY(T, Av0, Av1) do {                                           \
        asm volatile("s_waitcnt vmcnt(10)" ::: "memory");                      \
        __builtin_amdgcn_s_barrier();                                          \
        STAGE(((T) + 3) & 127, ((T) + 3) & 3);                                 \
        f16x8 ah, al;                                                          \
        {                                                                      \
            const float afv[8] = {Av0.x, Av0.y, Av0.z, Av0.w,                  \
                                  Av1.x, Av1.y, Av1.z, Av1.w};                 \
            _Pragma("unroll")                                                  \
            for (int j = 0; j < 8; ++j) {                                      \
                _Float16 h = (_Float16)afv[j];                                 \
                ah[j] = h;                                                     \
                al[j] = (_Float16)((afv[j] - (float)h) * 2048.f);              \
            }                                                                  \
        }                                                                      \
        LOADA(((T) + 2) & 127, Av0, Av1);                                      \
        const char* buf = lds + (((T) & 3) << 15);                             \
        _Pragma("unroll")                                                      \
        for (int f = 0; f < 8; ++f) {                                          \
            const int colf = 128 * cg + 16 * f + q;                            \
            const int off  = colf * 64 + ((g ^ sw) << 4);                      \
            f16x8 bh = *reinterpret_cast<const f16x8*>(buf + off);             \
            f16x8 bl = *reinterpret_cast<const f16x8*>(buf + 16384 + off);     \
            acc0[f] = __builtin_amdgcn_mfma_f32_16x16x32_f16(ah, bh, acc0[f], 0, 0, 0); \
            acc1[f] = __builtin_amdgcn_mfma_f32_16x16x32_f16(ah, bl, acc1[f], 0, 0, 0); \
            acc1[f] = __builtin_amdgcn_mfma_f32_16x16x32_f16(al, bh, acc1[f], 0, 0, 0); \
        }                                                                      \
    } while (0)

    #pragma unroll 1
    for (int u = 0; u < 64; ++u) {
        const int t0 = 2 * u;
        CHUNK_BODY(t0, aA0, aA1);
        CHUNK_BODY(t0 + 1, aB0, aB1);
    }
#undef CHUNK_BODY

    __syncthreads();   // full drain (vmcnt 0 incl. wrapped stages) before LDS reuse

    // ---- epilogue ----
    // LDS reuse: Hs[32][257] @0 (32896B); W1s_s @40000 (10x256 f32);
    // stats_s @50240 (32x10); cb_s @51520 (256); then H2 @40000, H3 @56512.
    float* W1s_s   = reinterpret_cast<float*>(lds + 40000);
    float* stats_s = reinterpret_cast<float*>(lds + 50240);
    float* cb_s    = reinterpret_cast<float*>(lds + 51520);
    float* Hs      = reinterpret_cast<float*>(lds);

    for (int i = tid; i < 2560; i += 256) {
        const int s = i >> 8, cc = i & 255;
        W1s_s[i] = W1[(size_t)(4165 + s) * 256 + cc];
    }
    for (int i = tid; i < 320; i += 256)
        stats_s[i] = stats[(size_t)row0 * 10 + i];
    cb_s[tid] = cbias[tid];
    __syncthreads();

    #pragma unroll
    for (int j = 0; j < 4; ++j) {
        const int m = g * 4 + j;        // C/D layout: row=(lane>>4)*4+j, col=lane&15
        const int grow = 16 * r + m;
        float s10[10];
        #pragma unroll
        for (int s = 0; s < 10; ++s) s10[s] = stats_s[grow * 10 + s];
        #pragma unroll
        for (int f = 0; f < 8; ++f) {
            const int colf = 128 * cg + 16 * f + q;
            float h = acc0[f][j] + acc1[f][j] * (1.f / 2048.f) + cb_s[colf];
            #pragma unroll
            for (int s = 0; s < 10; ++s) h += s10[s] * W1s_s[s * 256 + colf];
            Hs[grow * 257 + colf] = fmaxf(h, 0.f);
        }
    }
    __syncthreads();

    // layer 2: [32x256] @ [256x128] -> H2
    float* H2 = reinterpret_cast<float*>(lds + 40000);   // [32][129]
    {
        const int rr = tid >> 3;
        const int c0 = (tid & 7) * 16;
        float a2[16];
        #pragma unroll
        for (int i = 0; i < 16; ++i) a2[i] = b2[c0 + i];
        for (int k = 0; k < 256; ++k) {
            const float hv = Hs[rr * 257 + k];
            const float4 w0 = *reinterpret_cast<const float4*>(W2 + (size_t)k * 128 + c0);
            const float4 w1 = *reinterpret_cast<const float4*>(W2 + (size_t)k * 128 + c0 + 4);
            const float4 w2 = *reinterpret_cast<const float4*>(W2 + (size_t)k * 128 + c0 + 8);
            const float4 w3 = *reinterpret_cast<const float4*>(W2 + (size_t)k * 128 + c0 + 12);
            const float wvv[16] = {w0.x,w0.y,w0.z,w0.w, w1.x,w1.y,w1.z,w1.w,
                                   w2.x,w2.y,w2.z,w2.w, w3.x,w3.y,w3.z,w3.w};
            #pragma unroll
            for (int i = 0; i < 16; ++i) a2[i] += hv * wvv[i];
        }
        __syncthreads();   // all Hs-phase reads done before H2 overwrites region
        #pragma unroll
        for (int i = 0; i < 16; ++i)
            H2[rr * 129 + c0 + i] = fmaxf(a2[i], 0.f);
    }
    __syncthreads();

    // layer 3: [32x128] @ [128x64] -> H3
    float* H3 = reinterpret_cast<float*>(lds + 56512);   // [32][65]
    {
        const int rr = tid >> 3;
        const int c0 = (tid & 7) * 8;
        float a3[8];
        #pragma unroll
        for (int i = 0; i < 8; ++i) a3[i] = b3[c0 + i];
        for (int k = 0; k < 128; ++k) {
            const float hv = H2[rr * 129 + k];
            const float4 w0 = *reinterpret_cast<const float4*>(W3 + (size_t)k * 64 + c0);
            const float4 w1 = *reinterpret_cast<const float4*>(W3 + (size_t)k * 64 + c0 + 4);
            const float wvv[8] = {w0.x,w0.y,w0.z,w0.w, w1.x,w1.y,w1.z,w1.w};
            #pragma unroll
            for (int i = 0; i < 8; ++i) a3[i] += hv * wvv[i];
        }
        #pragma unroll
        for (int i = 0; i < 8; ++i)
            H3[rr * 65 + c0 + i] = fmaxf(a3[i], 0.f);
    }
    __syncthreads();

    // layer 4 + softmax: one thread per row
    if (tid < 32) {
        const int rr = tid;
        float lg[5];
        #pragma unroll
        for (int j = 0; j < 5; ++j) lg[j] = b4[j];
        for (int k = 0; k < 64; ++k) {
            const float hv = H3[rr * 65 + k];
            #pragma unroll
            for (int j = 0; j < 5; ++j) lg[j] += hv * W4[k * 5 + j];
        }
        float m = lg[0];
        #pragma unroll
        for (int j = 1; j < 5; ++j) m = fmaxf(m, lg[j]);
        float e[5], s = 0.f;
        #pragma unroll
        for (int j = 0; j < 5; ++j) { e[j] = expf(lg[j] - m); s += e[j]; }
        float* op = out + (size_t)(row0 + rr) * 5;
        #pragma unroll
        for (int j = 0; j < 5; ++j) op[j] = e[j] / s;
    }
}

// ---------------------------------------------------------------------------
extern "C" void kernel_launch(void* const* d_in, const int* in_sizes, int n_in,
                              void* d_out, int out_size, void* d_ws, size_t ws_size,
                              hipStream_t stream)
{
    const float* z   = (const float*)d_in[0];
    const int*   kp  = (const int*)d_in[1];
    const int*   tp  = (const int*)d_in[2];
    const int*   fp  = (const int*)d_in[3];
    const int*   sp  = (const int*)d_in[4];
    const int*   msp = (const int*)d_in[5];
    const float* W1  = (const float*)d_in[6];
    const float* b1  = (const float*)d_in[7];
    const float* W2  = (const float*)d_in[8];
    const float* b2  = (const float*)d_in[9];
    const float* W3  = (const float*)d_in[10];
    const float* b3  = (const float*)d_in[11];
    const float* W4  = (const float*)d_in[12];
    const float* b4  = (const float*)d_in[13];
    float* out = (float*)d_out;

    const int B = in_sizes[0] / DFEAT;             // 8192
    float* ws_stats = (float*)d_ws;                // [B][10]       (B*40 bytes)
    float* ws_cbias = ws_stats + (size_t)B * 10;   // [256]
    char*  ws_img   = (char*)(ws_cbias + 256);     // 128 x 32 KiB = 4 MiB

    hipLaunchKernelGGL(stats_kernel, dim3(B), dim3(256), 0, stream, z, ws_stats);
    hipLaunchKernelGGL(split_kernel, dim3(128), dim3(256), 0, stream, W1, ws_img);
    hipLaunchKernelGGL(prep_kernel, dim3(1), dim3(256), 0, stream,
                       kp, tp, fp, sp, msp, W1, b1, ws_cbias);
    hipLaunchKernelGGL(mlp_kernel, dim3(B / 32), dim3(256), 0, stream,
                       z, ws_img, W1, W2, b2, W3, b3, W4, b4,
                       ws_stats, ws_cbias, out);
}

// Round 7
// 463.692 us; speedup vs baseline: 1.9248x; 1.0880x over previous
//
#include <hip/hip_runtime.h>
#include <math.h>
#include <stdint.h>

#define DFEAT 4096
#define AS1 __attribute__((address_space(1)))
#define AS3 __attribute__((address_space(3)))

typedef _Float16 f16x8 __attribute__((ext_vector_type(8)));
typedef float f32x4 __attribute__((ext_vector_type(4)));

// ---------------------------------------------------------------------------
// Kernel 1: per-row stats, one WAVE per row. 64 keys/lane. Median via 32-round
// bit-descent where the wave count uses ballot+popcount (no shuffles, no LDS,
// no barriers; count is wave-uniform via the ballot mask).
// stats[r][0..9] = mean, std(ddof=1), min, max, lower-median, var, l2, l1, pos, neg
// ---------------------------------------------------------------------------
__global__ __launch_bounds__(256) void stats_kernel(const float* __restrict__ z,
                                                    float* __restrict__ stats)
{
    const int lane = threadIdx.x & 63;
    const int wv   = threadIdx.x >> 6;
    const int row  = blockIdx.x * 4 + wv;
    const float* zr = z + (size_t)row * DFEAT;

    unsigned keys[64];
    float sum = 0.f, ss = 0.f, l1 = 0.f;
    float mn = INFINITY, mx = -INFINITY;
    int pos = 0, neg = 0;

    #pragma unroll 4
    for (int j = 0; j < 16; ++j) {
        float4 v = reinterpret_cast<const float4*>(zr)[lane + j * 64];
        float vv[4] = {v.x, v.y, v.z, v.w};
        #pragma unroll
        for (int e = 0; e < 4; ++e) {
            float x = vv[e];
            sum += x; ss += x * x; l1 += fabsf(x);
            mn = fminf(mn, x); mx = fmaxf(mx, x);
            pos += (x > 0.f) ? 1 : 0;
            neg += (x < 0.f) ? 1 : 0;
            unsigned u = __float_as_uint(x);
            keys[j * 4 + e] = (u & 0x80000000u) ? ~u : (u | 0x80000000u);
        }
    }

    // one-time wave butterfly for the 7 streaming stats
    #pragma unroll
    for (int off = 1; off < 64; off <<= 1) {
        sum += __shfl_xor(sum, off);
        ss  += __shfl_xor(ss,  off);
        l1  += __shfl_xor(l1,  off);
        mn = fminf(mn, __shfl_xor(mn, off));
        mx = fmaxf(mx, __shfl_xor(mx, off));
        pos += __shfl_xor(pos, off);
        neg += __shfl_xor(neg, off);
    }

    // median: rank-2047 key. Per round: 64 ballots -> uniform count in SGPRs.
    unsigned lo = 0u;
    #pragma unroll 1
    for (int b = 31; b >= 0; --b) {
        const unsigned mid = lo | (1u << b);
        int cnt = 0;
        #pragma unroll
        for (int i = 0; i < 64; ++i)
            cnt += (int)__popcll(__ballot(keys[i] < mid));
        if (cnt <= 2047) lo = mid;     // wave-uniform decision
    }

    if (lane == 0) {
        const float med = (lo & 0x80000000u) ? __uint_as_float(lo ^ 0x80000000u)
                                             : __uint_as_float(~lo);
        const float n = (float)DFEAT;
        const float mean = sum / n;
        const float var = (ss - sum * sum / n) / (n - 1.f);
        float* sp = stats + (size_t)row * 10;
        sp[0] = mean;
        sp[1] = sqrtf(var);
        sp[2] = mn;
        sp[3] = mx;
        sp[4] = med;
        sp[5] = var;
        sp[6] = sqrtf(ss);
        sp[7] = l1;
        sp[8] = (float)pos;
        sp[9] = (float)neg;
    }
}

// ---------------------------------------------------------------------------
// Kernel 2: split W1[0:4096][256] into f16 (high, residual*2048) pre-swizzled
// LDS-image chunks: img[k0/32][32 KiB]; within a chunk:
//   Bh granule: byte = col*64 + ((g ^ ((col>>1)&3))<<4)  holds B[k0+g*8 .. +7][col]
//   Bl section at +16384 (same layout)
// ---------------------------------------------------------------------------
__global__ __launch_bounds__(256) void split_kernel(const float* __restrict__ W1,
                                                    char* __restrict__ img)
{
    const int c   = blockIdx.x;     // k-chunk 0..127
    const int col = threadIdx.x;    // 0..255
    const int k0  = c * 32;
    _Float16 h16[32], l16[32];
    #pragma unroll
    for (int kk = 0; kk < 32; ++kk) {
        float w = W1[(size_t)(k0 + kk) * 256 + col];
        _Float16 h = (_Float16)w;
        float rr = (w - (float)h) * 2048.f;
        h16[kk] = h;
        l16[kk] = (_Float16)rr;
    }
    char* base = img + (size_t)c * 32768;
    const int sw = (col >> 1) & 3;
    #pragma unroll
    for (int g = 0; g < 4; ++g) {
        f16x8 vh, vl;
        #pragma unroll
        for (int j = 0; j < 8; ++j) { vh[j] = h16[g * 8 + j]; vl[j] = l16[g * 8 + j]; }
        const int off = col * 64 + ((g ^ sw) << 4);
        *reinterpret_cast<f16x8*>(base + off)         = vh;
        *reinterpret_cast<f16x8*>(base + 16384 + off) = vl;
    }
}

// ---------------------------------------------------------------------------
// Kernel 3: cbias[256] = b1 + k_embed @ W1[4096:4160] + pos_enc @ W1[4160:4165]
// ---------------------------------------------------------------------------
__global__ __launch_bounds__(256) void prep_kernel(const int* kp, const int* tp,
                                                   const int* fp, const int* sp,
                                                   const int* msp,
                                                   const float* __restrict__ W1,
                                                   const float* __restrict__ b1,
                                                   float* __restrict__ cbias)
{
    __shared__ float ke[64];
    __shared__ float pe[5];
    const int tid = threadIdx.x;
    if (tid < 32) {
        const float c = (float)(-log(10000.0) / 31.0);
        const float freq = expf((float)tid * c);
        const float e = (float)(*kp) * freq;
        const double ed = (double)e;
        ke[tid]      = (float)sin(ed);
        ke[tid + 32] = (float)cos(ed);
    }
    if (tid == 0) {
        const float tf = (float)(*tp), ff = (float)(*fp);
        pe[0] = (float)sin((double)(0.1f * tf));
        pe[1] = (float)cos((double)(0.1f * tf));
        pe[2] = (float)sin((double)(0.1f * ff));
        pe[3] = (float)cos((double)(0.1f * ff));
        pe[4] = (float)(*sp) / (float)(*msp);
    }
    __syncthreads();
    float acc = b1[tid];
    #pragma unroll 8
    for (int i = 0; i < 64; ++i) acc += ke[i] * W1[(size_t)(4096 + i) * 256 + tid];
    #pragma unroll
    for (int i = 0; i < 5; ++i)  acc += pe[i] * W1[(size_t)(4160 + i) * 256 + tid];
    cbias[tid] = acc;
}

// ---------------------------------------------------------------------------
// Kernel 4: fused MLP, 512 threads = 8 waves = 2 K-halves x 4 col-quarters.
// Each wave: 32 rows x 64 cols over K=2048 (64 iters of K=32 per half).
// B-fragments reused across both row-tiles (halves LDS read volume).
// K-half partials combined through LDS; epilogue layers 2-4 + softmax in-block.
// ---------------------------------------------------------------------------
__global__ __launch_bounds__(512, 2) void mlp_kernel(
    const float* __restrict__ z, const char* __restrict__ img,
    const float* __restrict__ W1, const float* __restrict__ W2,
    const float* __restrict__ b2, const float* __restrict__ W3,
    const float* __restrict__ b3, const float* __restrict__ W4,
    const float* __restrict__ b4, const float* __restrict__ stats,
    const float* __restrict__ cbias, float* __restrict__ out)
{
    __shared__ char lds[131072];   // 2 x 64 KiB dbuf (each = kh0|kh1 32K halves)

    const int tid  = threadIdx.x;
    const int wv   = tid >> 6;           // 0..7
    const int kh   = wv >> 2;            // K-half
    const int wc   = wv & 3;             // col quarter (64 cols)
    const int lane = tid & 63;
    const int q    = lane & 15;
    const int g    = lane >> 4;
    const int row0 = blockIdx.x * 32;

    f32x4 acc0[2][4], acc1[2][4];
    #pragma unroll
    for (int rt = 0; rt < 2; ++rt)
        #pragma unroll
        for (int f = 0; f < 4; ++f) {
            acc0[rt][f] = (f32x4){0.f, 0.f, 0.f, 0.f};
            acc1[rt][f] = (f32x4){0.f, 0.f, 0.f, 0.f};
        }

    // A rows q and q+16 of this block, K base = kh*2048, k = t*32 + 8g + j
    const float* arow0 = z + (size_t)(row0 + q) * DFEAT + kh * 2048 + g * 8;
    const float* arow1 = arow0 + (size_t)16 * DFEAT;
    const int sw = (q >> 1) & 3;

    // stage both kh chunk images (64 KB total) into dst buffer: 8 x 16B/thread
    auto STAGE = [&](int t, char* dst) {
        const char* s0 = img + ((size_t)t << 15) + tid * 16;          // kh0: chunk t
        const char* s1 = img + ((size_t)(t + 64) << 15) + tid * 16;   // kh1: chunk t+64
        #pragma unroll
        for (int i = 0; i < 4; ++i) {
            __builtin_amdgcn_global_load_lds((const AS1 void*)(s0 + i * 8192),
                                             (AS3 void*)(dst + i * 8192 + tid * 16), 16, 0, 0);
            __builtin_amdgcn_global_load_lds((const AS1 void*)(s1 + i * 8192),
                                             (AS3 void*)(dst + 32768 + i * 8192 + tid * 16), 16, 0, 0);
        }
    };

    float4 a00, a01, a10, a11;
    auto LOADA = [&](int t) {
        const float* p0 = arow0 + t * 32;
        const float* p1 = arow1 + t * 32;
        a00 = *reinterpret_cast<const float4*>(p0);
        a01 = *reinterpret_cast<const float4*>(p0 + 4);
        a10 = *reinterpret_cast<const float4*>(p1);
        a11 = *reinterpret_cast<const float4*>(p1 + 4);
    };

    STAGE(0, lds);
    LOADA(0);
    __syncthreads();

    for (int t = 0; t < 64; ++t) {
        char* buf  = lds + ((t & 1) << 16);
        char* nbuf = lds + (((t + 1) & 1) << 16);
        if (t + 1 < 64) STAGE(t + 1, nbuf);

        // convert both A row-tiles to (high, residual*2048) f16
        f16x8 ah0, al0, ah1, al1;
        {
            const float f0[8] = {a00.x, a00.y, a00.z, a00.w, a01.x, a01.y, a01.z, a01.w};
            const float f1[8] = {a10.x, a10.y, a10.z, a10.w, a11.x, a11.y, a11.z, a11.w};
            #pragma unroll
            for (int j = 0; j < 8; ++j) {
                _Float16 h0 = (_Float16)f0[j];
                ah0[j] = h0;
                al0[j] = (_Float16)((f0[j] - (float)h0) * 2048.f);
                _Float16 h1 = (_Float16)f1[j];
                ah1[j] = h1;
                al1[j] = (_Float16)((f1[j] - (float)h1) * 2048.f);
            }
        }
        if (t + 1 < 64) LOADA(t + 1);

        const char* bb = buf + kh * 32768;
        #pragma unroll
        for (int f = 0; f < 4; ++f) {
            const int colf = 64 * wc + 16 * f + q;
            const int off  = colf * 64 + ((g ^ sw) << 4);
            f16x8 bh = *reinterpret_cast<const f16x8*>(bb + off);
            f16x8 bl = *reinterpret_cast<const f16x8*>(bb + 16384 + off);
            acc0[0][f] = __builtin_amdgcn_mfma_f32_16x16x32_f16(ah0, bh, acc0[0][f], 0, 0, 0);
            acc1[0][f] = __builtin_amdgcn_mfma_f32_16x16x32_f16(ah0, bl, acc1[0][f], 0, 0, 0);
            acc1[0][f] = __builtin_amdgcn_mfma_f32_16x16x32_f16(al0, bh, acc1[0][f], 0, 0, 0);
            acc0[1][f] = __builtin_amdgcn_mfma_f32_16x16x32_f16(ah1, bh, acc0[1][f], 0, 0, 0);
            acc1[1][f] = __builtin_amdgcn_mfma_f32_16x16x32_f16(ah1, bl, acc1[1][f], 0, 0, 0);
            acc1[1][f] = __builtin_amdgcn_mfma_f32_16x16x32_f16(al1, bh, acc1[1][f], 0, 0, 0);
        }
        __syncthreads();
    }

    // ---- epilogue (all regions disjoint) ----
    float* P_s     = reinterpret_cast<float*>(lds);            // [32][256]  @0
    float* Hs      = reinterpret_cast<float*>(lds + 32768);    // [32][257]
    float* W1s_s   = reinterpret_cast<float*>(lds + 65664);    // [10][256]
    float* stats_s = reinterpret_cast<float*>(lds + 75904);    // [32][10]
    float* cb_s    = reinterpret_cast<float*>(lds + 77184);    // [256]
    float* H2      = reinterpret_cast<float*>(lds + 78208);    // [32][129]
    float* H3      = reinterpret_cast<float*>(lds + 94720);    // [32][65]

    // kh1 waves write their combined partial; meanwhile load shared operands
    if (kh == 1) {
        #pragma unroll
        for (int rt = 0; rt < 2; ++rt)
            #pragma unroll
            for (int j = 0; j < 4; ++j) {
                const int grow = 16 * rt + 4 * g + j;
                #pragma unroll
                for (int f = 0; f < 4; ++f) {
                    const int colf = 64 * wc + 16 * f + q;
                    P_s[grow * 256 + colf] = acc0[rt][f][j] + acc1[rt][f][j] * (1.f / 2048.f);
                }
            }
    }
    for (int i = tid; i < 2560; i += 512) {
        const int s = i >> 8, cc = i & 255;
        W1s_s[i] = W1[(size_t)(4165 + s) * 256 + cc];
    }
    if (tid < 320) stats_s[tid] = stats[(size_t)row0 * 10 + tid];
    if (tid < 256) cb_s[tid] = cbias[tid];
    __syncthreads();

    // kh0 waves: final h1 = relu(own + P + cbias + stats @ W1s)
    if (kh == 0) {
        #pragma unroll
        for (int rt = 0; rt < 2; ++rt)
            #pragma unroll
            for (int j = 0; j < 4; ++j) {
                const int grow = 16 * rt + 4 * g + j;
                float s10[10];
                #pragma unroll
                for (int s = 0; s < 10; ++s) s10[s] = stats_s[grow * 10 + s];
                #pragma unroll
                for (int f = 0; f < 4; ++f) {
                    const int colf = 64 * wc + 16 * f + q;
                    float h = acc0[rt][f][j] + acc1[rt][f][j] * (1.f / 2048.f)
                            + P_s[grow * 256 + colf] + cb_s[colf];
                    #pragma unroll
                    for (int s = 0; s < 10; ++s) h += s10[s] * W1s_s[s * 256 + colf];
                    Hs[grow * 257 + colf] = fmaxf(h, 0.f);
                }
            }
    }
    __syncthreads();

    // layer 2: [32x256] @ [256x128] -> H2 ; 512 thr: 8 cols each
    {
        const int rr = tid >> 4;
        const int c0 = (tid & 15) * 8;
        float a2[8];
        #pragma unroll
        for (int i = 0; i < 8; ++i) a2[i] = b2[c0 + i];
        for (int k = 0; k < 256; ++k) {
            const float hv = Hs[rr * 257 + k];
            const float4 w0 = *reinterpret_cast<const float4*>(W2 + (size_t)k * 128 + c0);
            const float4 w1 = *reinterpret_cast<const float4*>(W2 + (size_t)k * 128 + c0 + 4);
            const float wvv[8] = {w0.x,w0.y,w0.z,w0.w, w1.x,w1.y,w1.z,w1.w};
            #pragma unroll
            for (int i = 0; i < 8; ++i) a2[i] += hv * wvv[i];
        }
        #pragma unroll
        for (int i = 0; i < 8; ++i)
            H2[rr * 129 + c0 + i] = fmaxf(a2[i], 0.f);
    }
    __syncthreads();

    // layer 3: [32x128] @ [128x64] -> H3 ; 512 thr: 4 cols each
    {
        const int rr = tid >> 4;
        const int c0 = (tid & 15) * 4;
        float a3[4];
        #pragma unroll
        for (int i = 0; i < 4; ++i) a3[i] = b3[c0 + i];
        for (int k = 0; k < 128; ++k) {
            const float hv = H2[rr * 129 + k];
            const float4 w0 = *reinterpret_cast<const float4*>(W3 + (size_t)k * 64 + c0);
            const float wvv[4] = {w0.x, w0.y, w0.z, w0.w};
            #pragma unroll
            for (int i = 0; i < 4; ++i) a3[i] += hv * wvv[i];
        }
        #pragma unroll
        for (int i = 0; i < 4; ++i)
            H3[rr * 65 + c0 + i] = fmaxf(a3[i], 0.f);
    }
    __syncthreads();

    // layer 4 + softmax: one thread per row
    if (tid < 32) {
        const int rr = tid;
        float lg[5];
        #pragma unroll
        for (int j = 0; j < 5; ++j) lg[j] = b4[j];
        for (int k = 0; k < 64; ++k) {
            const float hv = H3[rr * 65 + k];
            #pragma unroll
            for (int j = 0; j < 5; ++j) lg[j] += hv * W4[k * 5 + j];
        }
        float m = lg[0];
        #pragma unroll
        for (int j = 1; j < 5; ++j) m = fmaxf(m, lg[j]);
        float e[5], s = 0.f;
        #pragma unroll
        for (int j = 0; j < 5; ++j) { e[j] = expf(lg[j] - m); s += e[j]; }
        float* op = out + (size_t)(row0 + rr) * 5;
        #pragma unroll
        for (int j = 0; j < 5; ++j) op[j] = e[j] / s;
    }
}

// ---------------------------------------------------------------------------
extern "C" void kernel_launch(void* const* d_in, const int* in_sizes, int n_in,
                              void* d_out, int out_size, void* d_ws, size_t ws_size,
                              hipStream_t stream)
{
    const float* z   = (const float*)d_in[0];
    const int*   kp  = (const int*)d_in[1];
    const int*   tp  = (const int*)d_in[2];
    const int*   fp  = (const int*)d_in[3];
    const int*   sp  = (const int*)d_in[4];
    const int*   msp = (const int*)d_in[5];
    const float* W1  = (const float*)d_in[6];
    const float* b1  = (const float*)d_in[7];
    const float* W2  = (const float*)d_in[8];
    const float* b2  = (const float*)d_in[9];
    const float* W3  = (const float*)d_in[10];
    const float* b3  = (const float*)d_in[11];
    const float* W4  = (const float*)d_in[12];
    const float* b4  = (const float*)d_in[13];
    float* out = (float*)d_out;

    const int B = in_sizes[0] / DFEAT;             // 8192
    float* ws_stats = (float*)d_ws;                // [B][10]
    float* ws_cbias = ws_stats + (size_t)B * 10;   // [256]
    char*  ws_img   = (char*)(ws_cbias + 256);     // 128 x 32 KiB = 4 MiB

    hipLaunchKernelGGL(stats_kernel, dim3(B / 4), dim3(256), 0, stream, z, ws_stats);
    hipLaunchKernelGGL(split_kernel, dim3(128), dim3(256), 0, stream, W1, ws_img);
    hipLaunchKernelGGL(prep_kernel, dim3(1), dim3(256), 0, stream,
                       kp, tp, fp, sp, msp, W1, b1, ws_cbias);
    hipLaunchKernelGGL(mlp_kernel, dim3(B / 32), dim3(512), 0, stream,
                       z, ws_img, W1, W2, b2, W3, b3, W4, b4,
                       ws_stats, ws_cbias, out);
}